// Round 8
// baseline (1028.247 us; speedup 1.0000x reference)
//
#include <hip/hip_runtime.h>

typedef __bf16 bf16_t;
typedef __bf16 bf16x2 __attribute__((ext_vector_type(2)));
typedef __bf16 bf16x8 __attribute__((ext_vector_type(8)));
typedef float f32x4 __attribute__((ext_vector_type(4)));

#define MFMA_BF16(a, b, c) __builtin_amdgcn_mfma_f32_16x16x32_bf16((a), (b), (c), 0, 0, 0)

static constexpr int Bn = 4096;
static constexpr int Dn = 1024;
static constexpr int Rn = 256;
static constexpr int BT = 16;          // rows per block (one MFMA M-tile)
static constexpr int V_STRIDE = 1032;  // bf16 words
static constexpr int T_STRIDE = 264;
static constexpr int XS = 1028;        // fp32 words
static constexpr float DTv = 0.01f;
static constexpr float HDT = 0.005f;

// ---- Pack U [D=1024, R=256] fp32 -> bf16 B-operand fragment layout ----
// Upk[((ct*32 + kb)*64 + lane)*8 + j] = U[kb*32 + (lane>>4)*8 + j][ct*16 + (lane&15)]
__global__ void pack_u_kernel(const float* __restrict__ U, bf16_t* __restrict__ Upk) {
  int t = blockIdx.x * blockDim.x + threadIdx.x;  // 16*32*64 = 32768 threads
  int l = t & 63;
  int f = t >> 6;
  int kb = f & 31;
  int ct = f >> 5;
  int row0 = kb * 32 + (l >> 4) * 8;
  int col = ct * 16 + (l & 15);
  bf16x8 v;
#pragma unroll
  for (int j = 0; j < 8; ++j) v[j] = (bf16_t)U[(size_t)(row0 + j) * Rn + col];
  ((bf16x8*)Upk)[t] = v;
}

// ---- Pack W [R=256, D=1024] fp32 -> bf16 B-operand fragment layout ----
// Wpk[((ct*8 + kb)*64 + lane)*8 + j] = W[kb*32 + (lane>>4)*8 + j][ct*16 + (lane&15)]
__global__ void pack_w_kernel(const float* __restrict__ W, bf16_t* __restrict__ Wpk) {
  int t = blockIdx.x * blockDim.x + threadIdx.x;  // 64*8*64 = 32768 threads
  int l = t & 63;
  int f = t >> 6;
  int kb = f & 7;
  int ct = f >> 3;
  int row0 = kb * 32 + (l >> 4) * 8;
  int col = ct * 16 + (l & 15);
  bf16x8 v;
#pragma unroll
  for (int j = 0; j < 8; ++j) v[j] = (bf16_t)W[(size_t)(row0 + j) * Dn + col];
  ((bf16x8*)Wpk)[t] = v;
}

// ---- Fused integrator: 256 blocks x 512 threads; block owns 16 rows for all steps ----
// REGIME CHANGE (R8): 1024-thread blocks pin the backend to a 64-VGPR budget
// (R3-R7: immovable via launch_bounds / waves_per_eu / LDS) and its scheduler's
// load-hoisting then spills ~16 regs/iter (~270 MB scratch writes/dispatch,
// which thrashes L2 and evicts the U/W fragment set -> 1.9 GB HBM fetch).
// At 512 threads + 107 KB LDS: 1 block/CU = 2 waves/SIMD -> 256-VGPR budget.
// Peak demand ~125 incl. deep prefetch rings -> no spills, and ILP (depth-4
// rings) covers L2 latency at low occupancy.
//
// Wave wv (0..7): phase 1 computes R-cts {2wv,2wv+1} of hv = v@U;
// phase 2 computes D-cts 8wv..8wv+7 of gamma = T@W == its own 128 state cols.
__global__ __launch_bounds__(512)
void integrate_kernel(const float* __restrict__ x_in, const float* __restrict__ v_in,
                      const float* __restrict__ force,
                      const bf16_t* __restrict__ Upk, const bf16_t* __restrict__ Wpk,
                      const int* __restrict__ steps_p, float* __restrict__ out) {
  __shared__ __align__(16) bf16_t vbf[BT * V_STRIDE];  // v tile (x tile during phase 0)
  __shared__ __align__(16) bf16_t tbf[BT * T_STRIDE];  // T = tanh(hx)*hv^2 tile
  __shared__ __align__(16) float xls[BT * XS];         // fp32 x state

  const int tid = (int)threadIdx.x;
  const int wv = tid >> 6;   // 0..7
  const int l = tid & 63;
  const int ln = l & 15;
  const int quad = l >> 4;
  const int nhalf = 2 * steps_p[0];
  const int row_base = (int)blockIdx.x * BT;

  float* out_x = out;
  float* out_v = out + (size_t)Bn * Dn;

  // Register state, C/D layout. Element (j,r): row row_base+quad*4+r, col (wv*8+j)*16+ln
  float vs[8][4];                    // 32 regs
  bf16x2 fs2[8][2];                  // force, packed bf16 (16 regs)
  f32x4 hx0 = {0.f, 0.f, 0.f, 0.f};  // cached (x@U), ct = 2wv
  f32x4 hx1 = {0.f, 0.f, 0.f, 0.f};  // cached (x@U), ct = 2wv+1

  // B-fragment stream bases
  const bf16x8* up0 = (const bf16x8*)Upk + (size_t)(2 * wv) * 32 * 64 + l;  // ct=2wv
  const bf16x8* up1 = up0 + 32 * 64;                                        // ct=2wv+1
  const bf16x8* wp = (const bf16x8*)Wpk + (size_t)(wv * 8) * 8 * 64 + l;    // cts 8wv..8wv+7

  // {a0,a1} += tile(vbf)[16xD] @ U[:, cts 2wv,2wv+1]; depth-4 rings per stream
  auto gemm_u2 = [&](f32x4& a0, f32x4& a1) {
    const bf16_t* arow = vbf + ln * V_STRIDE + quad * 8;
    bf16x8 r0[4], r1[4];
#pragma unroll
    for (int p = 0; p < 4; ++p) {
      r0[p] = up0[p * 64];
      r1[p] = up1[p * 64];
    }
#pragma unroll
    for (int kb = 0; kb < 32; ++kb) {
      const bf16x8 a = *(const bf16x8*)(arow + kb * 32);
      const bf16x8 b0 = r0[kb & 3];
      const bf16x8 b1 = r1[kb & 3];
      if (kb < 28) {
        r0[kb & 3] = up0[(kb + 4) * 64];
        r1[kb & 3] = up1[(kb + 4) * 64];
      }
      a0 = MFMA_BF16(a, b0, a0);
      a1 = MFMA_BF16(a, b1, a1);
    }
  };

  // ---- init: load x,v,force; x -> xls (fp32) and vbf (bf16) for phase 0 ----
#pragma unroll
  for (int j = 0; j < 8; ++j) {
    const int col = (wv * 8 + j) * 16 + ln;
#pragma unroll
    for (int r = 0; r < 4; ++r) {
      const size_t g = (size_t)(row_base + quad * 4 + r) * Dn + col;
      const float xv = x_in[g];
      xls[(quad * 4 + r) * XS + col] = xv;
      vs[j][r] = v_in[g];
      fs2[j][r >> 1][r & 1] = (bf16_t)force[g];
      vbf[(quad * 4 + r) * V_STRIDE + col] = (bf16_t)xv;
    }
  }
  __syncthreads();

  // ---- phase 0: hx = x0 @ U ----
  gemm_u2(hx0, hx1);
  __syncthreads();  // everyone done reading x tile
#pragma unroll
  for (int j = 0; j < 8; ++j) {
    const int col = (wv * 8 + j) * 16 + ln;
#pragma unroll
    for (int r = 0; r < 4; ++r)
      vbf[(quad * 4 + r) * V_STRIDE + col] = (bf16_t)vs[j][r];
  }
  __syncthreads();

  for (int h = 0; h < nhalf; ++h) {
    // ---- phase 1: hv(cts 2wv,2wv+1) = v @ U ----
    f32x4 hv0 = {0.f, 0.f, 0.f, 0.f};
    f32x4 hv1 = {0.f, 0.f, 0.f, 0.f};
    gemm_u2(hv0, hv1);

    const bool odd = (h & 1) != 0;
    if (odd) {  // x was updated with exactly this v: hx += dt * hv
#pragma unroll
      for (int r = 0; r < 4; ++r) {
        hx0[r] += DTv * hv0[r];
        hx1[r] += DTv * hv1[r];
      }
    }
    // T = tanh(hx) * hv^2 -> tbf (bf16), cts 2wv, 2wv+1
#pragma unroll
    for (int i = 0; i < 2; ++i) {
      const f32x4 hxv = i ? hx1 : hx0;
      const f32x4 hvv = i ? hv1 : hv0;
      const int col = (2 * wv + i) * 16 + ln;
#pragma unroll
      for (int r = 0; r < 4; ++r) {
        float a = fminf(fmaxf(hxv[r], -15.f), 15.f);
        const float e = __expf(2.f * a);
        const float gate = (e - 1.f) / (e + 1.f);
        tbf[(quad * 4 + r) * T_STRIDE + col] = (bf16_t)(gate * hvv[r] * hvv[r]);
      }
    }
    __syncthreads();

    // ---- phase 2: gamma = T @ W, 2 passes x 4 ct-streams (depth-2); fold ----
#pragma unroll
    for (int p = 0; p < 2; ++p) {
      const bf16x8* wpp = wp + (size_t)(p * 4) * 8 * 64;  // cts 8wv+4p..+3
      f32x4 acc[4];
#pragma unroll
      for (int i = 0; i < 4; ++i) acc[i] = (f32x4){0.f, 0.f, 0.f, 0.f};
      const bf16_t* trow = tbf + ln * T_STRIDE + quad * 8;
      bf16x8 w[4][2];
#pragma unroll
      for (int i = 0; i < 4; ++i) {
        w[i][0] = wpp[i * 8 * 64];
        w[i][1] = wpp[i * 8 * 64 + 64];
      }
#pragma unroll
      for (int kb = 0; kb < 8; ++kb) {
        const bf16x8 a = *(const bf16x8*)(trow + kb * 32);
#pragma unroll
        for (int i = 0; i < 4; ++i) {
          const bf16x8 b = w[i][kb & 1];
          if (kb < 6) w[i][kb & 1] = wpp[i * 8 * 64 + (kb + 2) * 64];
          acc[i] = MFMA_BF16(a, b, acc[i]);
        }
      }
      // fold: v += hdt*(force - gamma); even h: x += dt*v (x in LDS); refresh vbf
#pragma unroll
      for (int i = 0; i < 4; ++i) {
        const int j = p * 4 + i;
        const int col = (wv * 8 + j) * 16 + ln;
#pragma unroll
        for (int r = 0; r < 4; ++r) {
          const float fval = (float)fs2[j][r >> 1][r & 1];
          vs[j][r] += HDT * (fval - acc[i][r]);
          if (!odd) xls[(quad * 4 + r) * XS + col] += DTv * vs[j][r];
          vbf[(quad * 4 + r) * V_STRIDE + col] = (bf16_t)vs[j][r];
        }
      }
    }
    __syncthreads();
  }

  // ---- store x, v ----
#pragma unroll
  for (int j = 0; j < 8; ++j) {
    const int col = (wv * 8 + j) * 16 + ln;
#pragma unroll
    for (int r = 0; r < 4; ++r) {
      const size_t g = (size_t)(row_base + quad * 4 + r) * Dn + col;
      out_x[g] = xls[(quad * 4 + r) * XS + col];
      out_v[g] = vs[j][r];
    }
  }
}

extern "C" void kernel_launch(void* const* d_in, const int* in_sizes, int n_in,
                              void* d_out, int out_size, void* d_ws, size_t ws_size,
                              hipStream_t stream) {
  const float* x = (const float*)d_in[0];
  const float* v = (const float*)d_in[1];
  const float* force = (const float*)d_in[2];
  const float* U = (const float*)d_in[3];
  const float* W = (const float*)d_in[4];
  const int* steps = (const int*)d_in[5];

  bf16_t* Upk = (bf16_t*)d_ws;                                  // 512 KB
  bf16_t* Wpk = (bf16_t*)((char*)d_ws + 16 * 32 * 64 * 8 * 2);  // next 512 KB

  pack_u_kernel<<<128, 256, 0, stream>>>(U, Upk);
  pack_w_kernel<<<128, 256, 0, stream>>>(W, Wpk);

  integrate_kernel<<<Bn / BT, 512, 0, stream>>>(x, v, force, Upk, Wpk, steps, (float*)d_out);
}